// Round 7
// baseline (63.522 us; speedup 1.0000x reference)
//
#include <hip/hip_runtime.h>
#include <hip/hip_bf16.h>

#define BB 2
#define TT 1024
#define DD 512
#define HH 8
#define FF 16
#define HDIM 64
#define BT (BB*TT)   // 2048

typedef short bf16x8 __attribute__((ext_vector_type(8)));
typedef float f32x4  __attribute__((ext_vector_type(4)));
#define MFMA_BF16 __builtin_amdgcn_mfma_f32_16x16x32_bf16

// float -> bf16 round-to-nearest-even (scalar)
__device__ __forceinline__ ushort f2b(float f) {
    uint u = __float_as_uint(f);
    uint r = (u + 0x7fffu + ((u >> 16) & 1u)) >> 16;
    return (ushort)r;
}

// pack two floats -> one dword of 2 bf16 (compiler: v_cvt_pk_bf16_f32)
__device__ __forceinline__ uint pkbf2(float a, float b) {
    __hip_bfloat162 h = __float22bfloat162_rn(make_float2(a, b));
    union { __hip_bfloat162 h2; uint u; } c; c.h2 = h;
    return c.u;
}

// load 8 f32, convert to bf16x8 fragment
__device__ __forceinline__ bf16x8 cvt8(const float* p) {
    float4 x = *(const float4*)p;
    float4 y = *(const float4*)(p + 4);
    union { bf16x8 v; uint u[4]; } r;
    r.u[0] = pkbf2(x.x, x.y);
    r.u[1] = pkbf2(x.z, x.w);
    r.u[2] = pkbf2(y.x, y.y);
    r.u[3] = pkbf2(y.z, y.w);
    return r.v;
}

// ---------------------------------------------------------------------------
// Kernel 1: QKV projection, bf16 MFMA, f32 inputs converted inline (no cast
// kernel).  C[2048 x 768] = X @ [Wq;Wk;Wv]^T, K=512.  64x64 tiles, 4 waves
// (2m x 2n), wave tile 32x32.  Grid (32, 13): by==12 blocks cast Wo -> Wob.
// Epilogue: Q,K -> (bh,t,16) bf16;  V -> Vt[bh][64][1024] (pre-transposed).
// ---------------------------------------------------------------------------
__global__ __launch_bounds__(256) void qkv_mfma(
    const float* __restrict__ X,  const float* __restrict__ Wq,
    const float* __restrict__ Wk, const float* __restrict__ Wv,
    const float* __restrict__ Wo,
    ushort* __restrict__ Qb, ushort* __restrict__ Kb,
    ushort* __restrict__ Vtg, ushort* __restrict__ Wob)
{
    if (blockIdx.y == 12) {   // Wo cast tail: 32 blocks x 256 thr x 8 float4
        const int idx = blockIdx.x * 256 + threadIdx.x;
        #pragma unroll
        for (int j = 0; j < 8; ++j) {
            const int u = j * 8192 + idx;          // 0..65535 float4s
            float4 v = *(const float4*)(Wo + (size_t)u * 4);
            ushort4 o = { f2b(v.x), f2b(v.y), f2b(v.z), f2b(v.w) };
            *(ushort4*)(Wob + (size_t)u * 4) = o;
        }
        return;
    }

    const int m0 = blockIdx.x * 64, n0 = blockIdx.y * 64;
    const int tid = threadIdx.x, w = tid >> 6, l = tid & 63;
    const int mw = w & 1, nw = w >> 1, lr = l & 15, g = l >> 4;

    const float* Wsrc; int nb0;
    if (n0 < 128)      { Wsrc = Wq; nb0 = n0; }
    else if (n0 < 256) { Wsrc = Wk; nb0 = n0 - 128; }
    else               { Wsrc = Wv; nb0 = n0 - 256; }

    f32x4 acc[2][2] = {};
    const float* Ar = X    + (size_t)(m0 + mw*32 + lr) * 512 + g*8;
    const float* Br = Wsrc + (size_t)(nb0 + nw*32 + lr) * 512 + g*8;

    #pragma unroll 4
    for (int ks = 0; ks < 16; ++ks) {
        bf16x8 a0 = cvt8(Ar + ks*32);
        bf16x8 a1 = cvt8(Ar + (size_t)16*512 + ks*32);
        bf16x8 b0 = cvt8(Br + ks*32);
        bf16x8 b1 = cvt8(Br + (size_t)16*512 + ks*32);
        acc[0][0] = MFMA_BF16(a0, b0, acc[0][0], 0, 0, 0);
        acc[0][1] = MFMA_BF16(a0, b1, acc[0][1], 0, 0, 0);
        acc[1][0] = MFMA_BF16(a1, b0, acc[1][0], 0, 0, 0);
        acc[1][1] = MFMA_BF16(a1, b1, acc[1][1], 0, 0, 0);
    }

    if (n0 < 256) {
        ushort* Dst = (n0 < 128) ? Qb : Kb;
        #pragma unroll
        for (int mb = 0; mb < 2; ++mb)
            #pragma unroll
            for (int nb = 0; nb < 2; ++nb) {
                const int nloc = nb0 + nw*32 + nb*16 + lr;    // 0..127
                const int h = nloc >> 4, f = nloc & 15;
                #pragma unroll
                for (int r = 0; r < 4; ++r) {
                    const int tok = m0 + mw*32 + mb*16 + g*4 + r;
                    const int b = tok >> 10, tt = tok & 1023;
                    Dst[(((size_t)(b*HH + h)) * TT + tt) * FF + f] = f2b(acc[mb][nb][r]);
                }
            }
    } else {
        #pragma unroll
        for (int mb = 0; mb < 2; ++mb)
            #pragma unroll
            for (int nb = 0; nb < 2; ++nb) {
                const int nloc = nb0 + nw*32 + nb*16 + lr;    // 0..511
                const int h = nloc >> 6, v = nloc & 63;
                const int tok0 = m0 + mw*32 + mb*16 + g*4;
                const int b = tok0 >> 10, tt = tok0 & 1023;
                uint2 pk = { pkbf2(acc[mb][nb][0], acc[mb][nb][1]),
                             pkbf2(acc[mb][nb][2], acc[mb][nb][3]) };
                *(uint2*)&Vtg[(((size_t)(b*HH + h)) * 64 + v) * TT + tt] = pk;
            }
    }
}

// ---------------------------------------------------------------------------
// Kernel 2: causal Taylor attention, bf16 MFMA, split-K across waves.
// phi(q).phi(k) = 1 + s + s^2/2, s = (q.k)/4.
// Grid: 1024 blocks = (qt 0..63 desc [LPT], bh 0..15). Block = 16 q-rows.
// Wave w: key-chunks kc = w, w+4, ... (64 keys each). Per chunk: QK^T via
// mfma(K,Q) (f=16 -> zeroed hi frags), poly+mask+den on C-regs, pack bf16
// -> LDS P (wave-local), PV with V-fragments straight from global Vtg (L2).
// Causal-boundary chunks clip fully-masked 16-key tiles (nmb), zero-filling
// the partial P tile. Partials combined once via LDS f32 scratch.
// ---------------------------------------------------------------------------
__global__ __launch_bounds__(256) void attn_mfma(
    const ushort* __restrict__ Qb, const ushort* __restrict__ Kb,
    const ushort* __restrict__ Vtg, ushort* __restrict__ Yb)
{
    __shared__ float smem[4416];                     // 17664 B
    short (*Pl)[16][72] = (short(*)[16][72])smem;    // [wave][q16][k64+8]
    float* scf = smem;                               // epi: [4][16][68]
    float* scd = smem + 4*16*68;                     // epi: [4][16]

    const int bid = blockIdx.x;
    const int qt = 63 - (bid >> 4);       // heavy q-tiles dispatch first (LPT)
    const int bh = bid & 15;
    const int b = bh >> 3, h = bh & 7;
    const int tid = threadIdx.x, w = tid >> 6, l = tid & 63;
    const int lr = l & 15, g = l >> 4;
    const int nkc = (qt + 4) >> 2;        // ceil((qt*16+16)/64)
    const bf16x8 zf = {0,0,0,0,0,0,0,0};

    bf16x8 qf = (l < 32)
        ? *(const bf16x8*)(Qb + ((size_t)bh*TT + qt*16 + lr)*FF + g*8)
        : zf;

    f32x4 o[4] = {};               // O^T partial: o[mv][r] = v-dim mv*16+g*4+r
    float den = 0.f;
    const int qg = qt*16 + lr;     // this lane's q index (C col = lr)
    const int qend = qt*16 + 16;

    for (int kc = w; kc < nkc; kc += 4) {
        const int act = qend - kc*64;                        // active keys, >=16
        const int nmb = (act >= 64) ? 4 : ((act + 15) >> 4); // live 16-key tiles
        const int kb_max = (nmb + 1) >> 1;

        for (int mb = 0; mb < nmb; ++mb) {
            bf16x8 kf = (l < 32)
                ? *(const bf16x8*)(Kb + ((size_t)bh*TT + kc*64 + mb*16 + lr)*FF + g*8)
                : zf;
            f32x4 z4 = {};
            f32x4 s = MFMA_BF16(kf, qf, z4, 0, 0, 0);
            const int kg0 = kc*64 + mb*16 + g*4;
            float pv[4];
            #pragma unroll
            for (int r = 0; r < 4; ++r) {
                float ss = s[r] * 0.25f;
                float pp = fmaf(ss, fmaf(ss, 0.5f, 1.0f), 1.0f);
                if (kg0 + r > qg) pp = 0.f;
                den += pp;
                pv[r] = pp;
            }
            uint2 pk = { pkbf2(pv[0], pv[1]), pkbf2(pv[2], pv[3]) };
            *(uint2*)&Pl[w][lr][mb*16 + g*4] = pk;
        }
        for (int mb = nmb; mb < kb_max*2; ++mb) {   // zero partial P tile
            uint2 zz = {0u, 0u};
            *(uint2*)&Pl[w][lr][mb*16 + g*4] = zz;
        }

        for (int kb = 0; kb < kb_max; ++kb) {
            bf16x8 pf = *(const bf16x8*)&Pl[w][lr][kb*32 + g*8];
            #pragma unroll
            for (int mv = 0; mv < 4; ++mv) {
                bf16x8 vf = *(const bf16x8*)(Vtg +
                    ((size_t)bh*64 + mv*16 + lr)*TT + kc*64 + kb*32 + g*8);
                o[mv] = MFMA_BF16(vf, pf, o[mv], 0, 0, 0);
            }
        }
    }

    // reduce den across the 4 lane groups (lanes sharing lr)
    float d = den;
    d += __shfl_xor(d, 16);
    d += __shfl_xor(d, 32);

    __syncthreads();   // all waves done with Pl (scratch overlays neighbors)

    #pragma unroll
    for (int mv = 0; mv < 4; ++mv)
        *(f32x4*)&scf[(size_t)(w*16 + lr)*68 + mv*16 + g*4] = o[mv];
    if (g == 0) scd[w*16 + lr] = d;

    __syncthreads();

    // combine 4 wave-partials, normalize, store bf16 Y (8B/thread coalesced)
    {
        const int q  = tid >> 4;           // 0..15
        const int v0 = (tid & 15) * 4;     // 0..60
        const float dtot = scd[q] + scd[16 + q] + scd[32 + q] + scd[48 + q];
        const float inv = 1.0f / (dtot + 1e-12f);
        float o0 = 0.f, o1 = 0.f, o2 = 0.f, o3 = 0.f;
        #pragma unroll
        for (int ww = 0; ww < 4; ++ww) {
            const float* p = &scf[(size_t)(ww*16 + q)*68 + v0];
            o0 += p[0]; o1 += p[1]; o2 += p[2]; o3 += p[3];
        }
        uint2 pk = { pkbf2(o0*inv, o1*inv), pkbf2(o2*inv, o3*inv) };
        *(uint2*)(Yb + ((size_t)(b*TT + qt*16 + q))*DD + h*HDIM + v0) = pk;
    }
}

// ---------------------------------------------------------------------------
// Kernel 3: output projection, bf16 MFMA.  Out[2048 x 512] = Yb @ Wob^T, f32.
// 32x64 tiles -> 512 blocks (2/CU), 4 waves (2m x 2n), wave tile 16x32.
// ---------------------------------------------------------------------------
__global__ __launch_bounds__(256) void out_mfma(
    const ushort* __restrict__ Yb, const ushort* __restrict__ Wob,
    float* __restrict__ Out)
{
    const int m0 = blockIdx.x * 32, n0 = blockIdx.y * 64;
    const int tid = threadIdx.x, w = tid >> 6, l = tid & 63;
    const int mw = w & 1, nw = w >> 1, lr = l & 15, g = l >> 4;

    f32x4 acc[2] = {};
    const ushort* Ar = Yb  + (size_t)(m0 + mw*16 + lr) * 512 + g*8;
    const ushort* Br = Wob + (size_t)(n0 + nw*32 + lr) * 512 + g*8;

    #pragma unroll 4
    for (int ks = 0; ks < 16; ++ks) {
        bf16x8 a0 = *(const bf16x8*)(Ar + ks*32);
        bf16x8 b0 = *(const bf16x8*)(Br + ks*32);
        bf16x8 b1 = *(const bf16x8*)(Br + (size_t)16*512 + ks*32);
        acc[0] = MFMA_BF16(a0, b0, acc[0], 0, 0, 0);
        acc[1] = MFMA_BF16(a0, b1, acc[1], 0, 0, 0);
    }

    #pragma unroll
    for (int nb = 0; nb < 2; ++nb) {
        const int n = n0 + nw*32 + nb*16 + lr;
        const int m = m0 + mw*16 + g*4;
        #pragma unroll
        for (int r = 0; r < 4; ++r)
            Out[(size_t)(m + r)*512 + n] = acc[nb][r];
    }
}

// ---------------------------------------------------------------------------
extern "C" void kernel_launch(void* const* d_in, const int* in_sizes, int n_in,
                              void* d_out, int out_size, void* d_ws, size_t ws_size,
                              hipStream_t stream) {
    const float* X  = (const float*)d_in[0];   // (2,1024,512)
    const float* Wq = (const float*)d_in[1];   // (128,512)
    const float* Wk = (const float*)d_in[2];   // (128,512)
    const float* Wv = (const float*)d_in[3];   // (512,512)
    const float* Wo = (const float*)d_in[4];   // (512,512)
    float* out = (float*)d_out;                // (2,1024,512)

    ushort* ws = (ushort*)d_ws;
    ushort* Wob = ws;                    // 512*512    = 262144
    ushort* Qb  = Wob + 262144;          // 16*1024*16 = 262144
    ushort* Kb  = Qb  + 262144;          // 262144
    ushort* Vtg = Kb  + 262144;          // 16*64*1024 = 1048576
    ushort* Yb  = Vtg + 1048576;         // 2048*512   = 1048576
    // total 2,883,584 ushorts = 5.8 MB

    dim3 g1(BT/64, 13);       // 32 x 12 GEMM + 32 x 1 Wo-cast = 416 blocks
    qkv_mfma<<<g1, 256, 0, stream>>>(X, Wq, Wk, Wv, Wo, Qb, Kb, Vtg, Wob);

    attn_mfma<<<1024, 256, 0, stream>>>(Qb, Kb, Vtg, Yb);

    dim3 g3(BT/32, DD/64);    // 64 x 8 = 512 blocks
    out_mfma<<<g3, 256, 0, stream>>>(Yb, Wob, out);
}